// Round 11
// baseline (110.331 us; speedup 1.0000x reference)
//
#include <hip/hip_runtime.h>
#include <hip/hip_bf16.h>

typedef __bf16 bf16_t;
typedef __bf16 bf16x4 __attribute__((ext_vector_type(4)));
typedef __bf16 bf16x8 __attribute__((ext_vector_type(8)));
typedef float f32x4 __attribute__((ext_vector_type(4)));

#define M_TOT 8192
#define N_TOT 512
#define K_TOT 2048
#define E_TOT 512
#define NSEG_HALF 16      // 16 segments of BK=64 per k-slice (K=2048 split x2)

__device__ __forceinline__ bf16x8 zero8() {
    bf16x8 v;
#pragma unroll
    for (int i = 0; i < 8; ++i) v[i] = (bf16_t)0.0f;
    return v;
}

// ---------------------------------------------------------------------------
// prep4 (unchanged; correctness-proven):
//  blocks [0,256):   LDS-tiled transpose W2[k][n] -> W2t[n][k] bf16
//  blocks [256,288): zb[m][0..8)=cos(theta[q])*cos(x[m,q]) (RX collapse:
//                    |a2|^2-|b2|^2 = cos(theta)*cos(x)); zb[m][8]=1; rest 0
//  blocks [288,296): W1p: permuted W1 rows + bias so h-MFMA C-output lands
//    exactly in main-MFMA A-fragment layout.
//    Row d=(c*2+p)*16+rr holds f = c*32+(rr>>2)*8+p*4+(rr&3).
// ---------------------------------------------------------------------------
__global__ __launch_bounds__(256)
void prep4_kernel(const float* __restrict__ x,
                  const float* __restrict__ theta,
                  const float* __restrict__ W1,
                  const float* __restrict__ b1,
                  const float* __restrict__ W2,
                  bf16_t* __restrict__ W2t,
                  bf16_t* __restrict__ zb,
                  bf16_t* __restrict__ W1p)
{
    const int b = blockIdx.x;
    if (b < 256) {
        __shared__ bf16_t T[64][66];
        const int k0 = (b >> 3) * 64;
        const int n0 = (b & 7) * 64;
        const int kl = threadIdx.x >> 4;
        const int n4 = threadIdx.x & 15;
#pragma unroll
        for (int i = 0; i < 4; ++i) {
            int k = kl + i * 16;
            float4 v = *(const float4*)(W2 + (size_t)(k0 + k) * N_TOT + n0 + n4 * 4);
            T[n4 * 4 + 0][k] = (bf16_t)v.x;
            T[n4 * 4 + 1][k] = (bf16_t)v.y;
            T[n4 * 4 + 2][k] = (bf16_t)v.z;
            T[n4 * 4 + 3][k] = (bf16_t)v.w;
        }
        __syncthreads();
        const int nl = threadIdx.x >> 4;
        const int k4 = threadIdx.x & 15;
#pragma unroll
        for (int i = 0; i < 4; ++i) {
            int n = nl + i * 16;
            bf16x4 v;
            v[0] = T[n][k4 * 4 + 0];
            v[1] = T[n][k4 * 4 + 1];
            v[2] = T[n][k4 * 4 + 2];
            v[3] = T[n][k4 * 4 + 3];
            *(bf16x4*)(W2t + (size_t)(n0 + n) * K_TOT + k0 + k4 * 4) = v;
        }
    } else if (b < 288) {
        const int m = (b - 256) * 256 + threadIdx.x;
        float4 x0 = *(const float4*)(x + (size_t)m * E_TOT);
        float4 x1 = *(const float4*)(x + (size_t)m * E_TOT + 4);
        float xs[8] = {x0.x, x0.y, x0.z, x0.w, x1.x, x1.y, x1.z, x1.w};
        bf16x8 lo;
#pragma unroll
        for (int q = 0; q < 8; ++q)
            lo[q] = (bf16_t)(__builtin_cosf(theta[q]) * __builtin_cosf(xs[q]));
        bf16x8 hi = zero8();
        hi[0] = (bf16_t)1.0f;                  // bias lane at k=8
        *(bf16x8*)(zb + (size_t)m * 16)     = lo;
        *(bf16x8*)(zb + (size_t)m * 16 + 8) = hi;
    } else {
        const int d  = (b - 288) * 256 + threadIdx.x;    // 0..2047
        const int c  = d >> 5;
        const int dd = d & 31;
        const int p  = dd >> 4;
        const int rr = dd & 15;
        const int f  = c * 32 + ((rr >> 2) << 3) + (p << 2) + (rr & 3);
        bf16x8 lo;
#pragma unroll
        for (int q = 0; q < 8; ++q)
            lo[q] = (bf16_t)W1[(size_t)q * K_TOT + f];
        bf16x8 hi = zero8();
        hi[0] = (bf16_t)b1[f];                 // bias at k=8
        *(bf16x8*)(W1p + (size_t)d * 16)     = lo;
        *(bf16x8*)(W1p + (size_t)d * 16 + 8) = hi;
    }
}

// ---------------------------------------------------------------------------
// helpers (256-thread block = 4 waves: 2 m-slots x 2 k-slices;
//          block tile 64m x 64n, per-slice segment BK=64)
// ---------------------------------------------------------------------------
// B segment: 64n x 64k bf16 = 8KB (one k-tile). LDS byte layout LINEAR in
// s (byte = s*16, s=0..511): n=(s>>3)&63, seg=s&7. XOR swizzle (slot seg
// holds global k-chunk g=seg^(n&7)) applied on the GLOBAL source address,
// LDS dest linear -> global_load_lds legal (wave-uniform base + lane*16);
// swizzled ds_read side unchanged.
__device__ __forceinline__ void stage_B(const bf16_t* __restrict__ W2t,
                                        bf16_t* dst_buf, int n_base, int k0,
                                        int wl, int l) {
#pragma unroll
    for (int j = 0; j < 4; ++j) {
        int s = wl * 64 + l + j * 128;     // this lane's 16B slot (0..511)
        int n = (s >> 3) & 63;
        int g = (s & 7) ^ (n & 7);
        const bf16_t* src = W2t + (size_t)(n_base + n) * K_TOT + k0 + g * 8;
        bf16_t* ldst = dst_buf + (size_t)(wl * 64 + j * 128) * 8;
        __builtin_amdgcn_global_load_lds(
            (const __attribute__((address_space(1))) unsigned int*)src,
            (__attribute__((address_space(3))) unsigned int*)ldst,
            16, 0, 0);
    }
}

// W1p frags for one 64-k tile (2 chunks x 2 perm-halves); lanes lq<2 real.
__device__ __forceinline__ void load_wf(const bf16_t* __restrict__ W1p, int k0,
                                        int l15, int lq, bf16x8 wf[4]) {
#pragma unroll
    for (int i = 0; i < 4; ++i) wf[i] = zero8();
    if (lq < 2) {
        const int base = (k0 >> 5) * 2;
#pragma unroll
        for (int i = 0; i < 4; ++i)
            wf[i] = *(const bf16x8*)(W1p + (size_t)((base + i) * 16 + l15) * 16 + lq * 8);
    }
}

// h-stage for one segment: REGISTER-ONLY (wf + zfrag -> af). Independent of
// LDS/B -> can run one segment ahead, overlapped with the previous segment's
// mains. Identical math/order to the proven fused version.
__device__ __forceinline__ void compute_h(const bf16x8 wf[4],
                                          const bf16x8 zfrag[2],
                                          bf16x8 af[2][2]) {
#pragma unroll
    for (int mt = 0; mt < 2; ++mt)
#pragma unroll
        for (int c = 0; c < 2; ++c) {
            f32x4 h0 = (f32x4){0.f, 0.f, 0.f, 0.f};
            f32x4 h1 = (f32x4){0.f, 0.f, 0.f, 0.f};
            h0 = __builtin_amdgcn_mfma_f32_16x16x32_bf16(wf[c * 2 + 0], zfrag[mt], h0, 0, 0, 0);
            h1 = __builtin_amdgcn_mfma_f32_16x16x32_bf16(wf[c * 2 + 1], zfrag[mt], h1, 0, 0, 0);
            bf16x8 a;
#pragma unroll
            for (int r = 0; r < 4; ++r) {
                a[r]     = (bf16_t)fmaxf(h0[r], 0.f);
                a[r + 4] = (bf16_t)fmaxf(h1[r], 0.f);
            }
            af[mt][c] = a;
        }
}

// main-stage for one segment: 8 ds_read_b128 + 16 main MFMAs, consuming a
// PRE-BUILT af (no h dependency on the critical path). MFMA order per acc
// register over (c,mt,nt) identical to the proven kernel -> bit-identical.
__device__ __forceinline__ void compute_main(const bf16_t* Bb,
                                             const bf16x8 af[2][2],
                                             int l15, int lq,
                                             f32x4 acc[2][4]) {
    bf16x8 bfr[2][4];
#pragma unroll
    for (int c = 0; c < 2; ++c)
#pragma unroll
        for (int nt = 0; nt < 4; ++nt) {
            int r = nt * 16 + l15;
            int s = (c * 4 + lq) ^ (r & 7);
            bfr[c][nt] = *(const bf16x8*)(Bb + r * 64 + s * 8);
        }
#pragma unroll
    for (int c = 0; c < 2; ++c)
#pragma unroll
        for (int mt = 0; mt < 2; ++mt)
#pragma unroll
            for (int nt = 0; nt < 4; ++nt)
                acc[mt][nt] = __builtin_amdgcn_mfma_f32_16x16x32_bf16(
                    af[mt][c], bfr[c][nt], acc[mt][nt], 0, 0, 0);
}

// ---------------------------------------------------------------------------
// Fused GEMM: out = relu(z@W1+b1) @ W2 + b2
// Block 64m x 64n, 256 thr = 4 waves = 2 m-slots (32m each) x 2 K-SLICES.
// Split-K x2; double-buffered BK=64 per slice (LDS 32KB/block);
// grid (8,128)=1024 blocks = 4 blocks/CU (16 waves/CU); LDS combine.
//
// R11 -- BREAK THE INTRA-WAVE h->relu->main CHAIN (the round's variable):
// GEMM time has been invariant to occupancy, LDS traffic, staging mechanism,
// barrier frequency, and VMEM order (R2-R10) -- every inter-wave lever is
// flat. The one constant: inside each segment the mains waited serially on
// {load_wf -> 4 h-MFMA -> AGPR-read latency -> ~50 VALU relu/cvt}. Now the
// h-stage for segment s+1 runs overlapped with the mains of segment s
// (af double-buffered afA/afB, manual 2x unroll for static indexing;
// ~+24 VGPR, fits the 128 cap at 4 blocks/CU). Per-segment critical path
// becomes max(mains, h) instead of h + mains.
// ---------------------------------------------------------------------------
__global__ __launch_bounds__(256, 4)
void ffq_gemm_kernel(const bf16_t* __restrict__ zb,    // [8192][16]
                     const bf16_t* __restrict__ W1p,   // [2048][16] permuted
                     const bf16_t* __restrict__ W2t,   // [512][2048]
                     const float* __restrict__ b2,
                     float* __restrict__ out)          // [8192][512]
{
    __shared__ bf16_t Blds[2][2][64 * 64];   // [kslice][buf][one 64x64 tile]

    const int t  = threadIdx.x;           // 0..255
    const int w  = t >> 6, l = t & 63;
    const int ks = w >> 1;                // k-slice 0/1
    const int wl = w & 1;                 // m-slot of 32 rows
    const int m_base = blockIdx.y * 64;
    const int n_base = blockIdx.x * 64;
    const int l15 = l & 15, lq = l >> 4;
    const int k_base = ks * 1024;

    // persistent z^T B-frags for this wave's two 16-row m-tiles
    bf16x8 zfrag[2];
#pragma unroll
    for (int mt = 0; mt < 2; ++mt) {
        zfrag[mt] = zero8();
        if (lq < 2)
            zfrag[mt] = *(const bf16x8*)(zb + (size_t)(m_base + wl * 32 + mt * 16 + l15) * 16 + lq * 8);
    }

    f32x4 acc[2][4];
#pragma unroll
    for (int mt = 0; mt < 2; ++mt)
#pragma unroll
        for (int nt = 0; nt < 4; ++nt)
            acc[mt][nt] = (f32x4){0.f, 0.f, 0.f, 0.f};

    // prologue: stage segment 0 -> buf0 (async; first barrier drains);
    // build af for segment 0 NOW (overlaps the staging latency).
    stage_B(W2t, Blds[ks][0], n_base, k_base, wl, l);
    bf16x8 afA[2][2], afB[2][2];
    {
        bf16x8 wf0[4];
        load_wf(W1p, k_base, l15, lq, wf0);
        compute_h(wf0, zfrag, afA);
    }

    // manual 2x unroll: even segment uses afA (builds afB), odd uses afB
    // (builds afA). All af indices static -> no scratch (rule #20).
    for (int sp = 0; sp < NSEG_HALF; sp += 2) {
        // ---- segment sp (buf0, afA) ----
        __syncthreads();                   // publish buf0 for seg sp
        {
            bf16x8 wf[4];
            const bool pre = true;          // sp+1 < 16 always (sp <= 14)
            load_wf(W1p, k_base + (sp + 1) * 64, l15, lq, wf);
            __builtin_amdgcn_sched_barrier(0);   // keep wf older than stage
            stage_B(W2t, Blds[ks][1], n_base, k_base + (sp + 1) * 64, wl, l);
            compute_main(Blds[ks][0], afA, l15, lq, acc);
            if (pre) compute_h(wf, zfrag, afB);
        }
        // ---- segment sp+1 (buf1, afB) ----
        __syncthreads();                   // publish buf1 for seg sp+1
        {
            const bool pre = (sp + 2 < NSEG_HALF);
            bf16x8 wf[4];
            if (pre) {
                load_wf(W1p, k_base + (sp + 2) * 64, l15, lq, wf);
                __builtin_amdgcn_sched_barrier(0);
                stage_B(W2t, Blds[ks][0], n_base, k_base + (sp + 2) * 64, wl, l);
            }
            compute_main(Blds[ks][1], afB, l15, lq, acc);
            if (pre) compute_h(wf, zfrag, afA);
        }
    }

    // ---- split-K combine through LDS (reuse Blds as f32 scratch) ----
    __syncthreads();                       // all LDS reads of B done
    float* F = (float*)&Blds[0][0][0];     // 16KB needed, 32KB available
    if (ks == 1) {
#pragma unroll
        for (int mt = 0; mt < 2; ++mt)
#pragma unroll
            for (int nt = 0; nt < 4; ++nt) {
                int idx = ((wl * 2 + mt) * 4 + nt) * 64 + l;   // lane-contig 16B
                *(f32x4*)(F + (size_t)idx * 4) = acc[mt][nt];
            }
    }
    __syncthreads();
    if (ks == 0) {
        // ---- epilogue: C/D layout col=lane&15, row=(lane>>4)*4+r ----
#pragma unroll
        for (int nt = 0; nt < 4; ++nt) {
            int col = n_base + nt * 16 + l15;
            float bias = b2[col];
#pragma unroll
            for (int mt = 0; mt < 2; ++mt) {
                int idx = ((wl * 2 + mt) * 4 + nt) * 64 + l;
                f32x4 part = *(const f32x4*)(F + (size_t)idx * 4);
#pragma unroll
                for (int r = 0; r < 4; ++r) {
                    int row = m_base + wl * 32 + mt * 16 + lq * 4 + r;
                    out[(size_t)row * N_TOT + col] = acc[mt][nt][r] + part[r] + bias;
                }
            }
        }
    }
}

extern "C" void kernel_launch(void* const* d_in, const int* in_sizes, int n_in,
                              void* d_out, int out_size, void* d_ws, size_t ws_size,
                              hipStream_t stream) {
    const float* x     = (const float*)d_in[0];
    const float* theta = (const float*)d_in[1];
    const float* W1    = (const float*)d_in[2];
    const float* b1    = (const float*)d_in[3];
    const float* W2    = (const float*)d_in[4];
    const float* b2    = (const float*)d_in[5];
    float* out = (float*)d_out;

    // ws: [0,2MB) W2t ; [2MB,2.25MB) zb[8192][16] ; then W1p[2048][16]
    const size_t W2T_BYTES = (size_t)N_TOT * K_TOT * sizeof(bf16_t);  // 2 MB
    const size_t ZB_BYTES  = (size_t)M_TOT * 16 * sizeof(bf16_t);     // 256 KB

    bf16_t* W2t = (bf16_t*)d_ws;
    bf16_t* zb  = (bf16_t*)((char*)d_ws + W2T_BYTES);
    bf16_t* W1p = (bf16_t*)((char*)d_ws + W2T_BYTES + ZB_BYTES);

    prep4_kernel<<<296, 256, 0, stream>>>(x, theta, W1, b1, W2, W2t, zb, W1p);

    dim3 grid(N_TOT / 64, M_TOT / 64);    // (8, 128) = 1024 blocks, 4/CU
    ffq_gemm_kernel<<<grid, 256, 0, stream>>>(zb, W1p, W2t, b2, out);
}

// Round 12
// 103.446 us; speedup vs baseline: 1.0665x; 1.0665x over previous
//
#include <hip/hip_runtime.h>
#include <hip/hip_bf16.h>

typedef __bf16 bf16_t;
typedef __bf16 bf16x4 __attribute__((ext_vector_type(4)));
typedef __bf16 bf16x8 __attribute__((ext_vector_type(8)));
typedef float f32x4 __attribute__((ext_vector_type(4)));

#define M_TOT 8192
#define N_TOT 512
#define K_TOT 2048
#define E_TOT 512
#define NSEG_HALF 16      // 16 tiles of BK=64 per k-slice (K=2048 split x2)

__device__ __forceinline__ bf16x8 zero8() {
    bf16x8 v;
#pragma unroll
    for (int i = 0; i < 8; ++i) v[i] = (bf16_t)0.0f;
    return v;
}

// ---------------------------------------------------------------------------
// prep4:
//  blocks [0,256):   W2[k][n] -> W2f FRAGMENT-MAJOR bf16 (changed in R12):
//    W2f is organized per (n_block 0..7, k_tile 0..31) as 4096 bf16:
//    chunk ci = c*256 + nt*64 + l (c:k-chunk-pair 0..1, nt:n-subtile 0..3,
//    l:lane 0..63), 8 bf16 each, where chunk holds
//    W2[k_tile*64 + (c*4+(l>>4))*8 + j][n_block*64 + nt*16 + (l&15)].
//    A wave's B-fragment read for (c,nt) is then ONE fully-coalesced
//    global_load_dwordx4 at base + (c*256+nt*64+l)*16B -- same base per
//    tile, immediate offsets, zero address VALU, L2-resident (2MB).
//  blocks [256,288): zb[m][0..8)=cos(theta[q])*cos(x[m,q]) (RX collapse);
//                    zb[m][8]=1; rest 0
//  blocks [288,296): W1p: permuted W1 rows + bias so h-MFMA C-output lands
//    exactly in main-MFMA A-fragment layout.
//    Row d=(c*2+p)*16+rr holds f = c*32+(rr>>2)*8+p*4+(rr&3).
// ---------------------------------------------------------------------------
__global__ __launch_bounds__(256)
void prep4_kernel(const float* __restrict__ x,
                  const float* __restrict__ theta,
                  const float* __restrict__ W1,
                  const float* __restrict__ b1,
                  const float* __restrict__ W2,
                  bf16_t* __restrict__ W2f,
                  bf16_t* __restrict__ zb,
                  bf16_t* __restrict__ W1p)
{
    const int b = blockIdx.x;
    if (b < 256) {
        __shared__ bf16_t T[64][66];
        const int k0 = (b >> 3) * 64;
        const int n0 = (b & 7) * 64;
        const int kl = threadIdx.x >> 4;
        const int n4 = threadIdx.x & 15;
#pragma unroll
        for (int i = 0; i < 4; ++i) {
            int k = kl + i * 16;
            float4 v = *(const float4*)(W2 + (size_t)(k0 + k) * N_TOT + n0 + n4 * 4);
            T[n4 * 4 + 0][k] = (bf16_t)v.x;
            T[n4 * 4 + 1][k] = (bf16_t)v.y;
            T[n4 * 4 + 2][k] = (bf16_t)v.z;
            T[n4 * 4 + 3][k] = (bf16_t)v.w;
        }
        __syncthreads();
        // write fragment-major: tile index = n_block*32 + k_tile
        const size_t base = (size_t)((b & 7) * 32 + (b >> 3)) * 4096;
#pragma unroll
        for (int i = 0; i < 2; ++i) {
            int ci = threadIdx.x + i * 256;        // chunk 0..511
            int c  = ci >> 8;
            int nt = (ci >> 6) & 3;
            int l  = ci & 63;
            int nl = nt * 16 + (l & 15);
            int kk = (c * 4 + (l >> 4)) * 8;
            bf16x8 v;
#pragma unroll
            for (int j = 0; j < 8; ++j) v[j] = T[nl][kk + j];
            *(bf16x8*)(W2f + base + (size_t)ci * 8) = v;
        }
    } else if (b < 288) {
        const int m = (b - 256) * 256 + threadIdx.x;
        float4 x0 = *(const float4*)(x + (size_t)m * E_TOT);
        float4 x1 = *(const float4*)(x + (size_t)m * E_TOT + 4);
        float xs[8] = {x0.x, x0.y, x0.z, x0.w, x1.x, x1.y, x1.z, x1.w};
        bf16x8 lo;
#pragma unroll
        for (int q = 0; q < 8; ++q)
            lo[q] = (bf16_t)(__builtin_cosf(theta[q]) * __builtin_cosf(xs[q]));
        bf16x8 hi = zero8();
        hi[0] = (bf16_t)1.0f;                  // bias lane at k=8
        *(bf16x8*)(zb + (size_t)m * 16)     = lo;
        *(bf16x8*)(zb + (size_t)m * 16 + 8) = hi;
    } else {
        const int d  = (b - 288) * 256 + threadIdx.x;    // 0..2047
        const int c  = d >> 5;
        const int dd = d & 31;
        const int p  = dd >> 4;
        const int rr = dd & 15;
        const int f  = c * 32 + ((rr >> 2) << 3) + (p << 2) + (rr & 3);
        bf16x8 lo;
#pragma unroll
        for (int q = 0; q < 8; ++q)
            lo[q] = (bf16_t)W1[(size_t)q * K_TOT + f];
        bf16x8 hi = zero8();
        hi[0] = (bf16_t)b1[f];                 // bias at k=8
        *(bf16x8*)(W1p + (size_t)d * 16)     = lo;
        *(bf16x8*)(W1p + (size_t)d * 16 + 8) = hi;
    }
}

// W1p frags for one 64-k tile (2 chunks x 2 perm-halves); lanes lq<2 real.
__device__ __forceinline__ void load_wf(const bf16_t* __restrict__ W1p, int k0,
                                        int l15, int lq, bf16x8 wf[4]) {
#pragma unroll
    for (int i = 0; i < 4; ++i) wf[i] = zero8();
    if (lq < 2) {
        const int base = (k0 >> 5) * 2;
#pragma unroll
        for (int i = 0; i < 4; ++i)
            wf[i] = *(const bf16x8*)(W1p + (size_t)((base + i) * 16 + l15) * 16 + lq * 8);
    }
}

// one 64-k tile, ALL operands via registers/global (no LDS, no barriers):
// 8 coalesced B-fragment loads from W2f (L2-resident) + h in registers
// (layout-matched MFMA) + 16 mains. Operand values and MFMA order per acc
// register identical to the proven R5/R9 kernels -> bit-identical numerics.
__device__ __forceinline__ void compute_tile(const bf16_t* __restrict__ tb,
                                             const bf16x8 wf[4],
                                             const bf16x8 zfrag[2],
                                             int l,
                                             f32x4 acc[2][4]) {
    bf16x8 bfr[2][4];
#pragma unroll
    for (int c = 0; c < 2; ++c)
#pragma unroll
        for (int nt = 0; nt < 4; ++nt)
            bfr[c][nt] = *(const bf16x8*)(tb + (size_t)(c * 256 + nt * 64 + l) * 8);

    bf16x8 af[2][2];
#pragma unroll
    for (int mt = 0; mt < 2; ++mt)
#pragma unroll
        for (int c = 0; c < 2; ++c) {
            f32x4 h0 = (f32x4){0.f, 0.f, 0.f, 0.f};
            f32x4 h1 = (f32x4){0.f, 0.f, 0.f, 0.f};
            h0 = __builtin_amdgcn_mfma_f32_16x16x32_bf16(wf[c * 2 + 0], zfrag[mt], h0, 0, 0, 0);
            h1 = __builtin_amdgcn_mfma_f32_16x16x32_bf16(wf[c * 2 + 1], zfrag[mt], h1, 0, 0, 0);
            bf16x8 a;
#pragma unroll
            for (int r = 0; r < 4; ++r) {
                a[r]     = (bf16_t)fmaxf(h0[r], 0.f);
                a[r + 4] = (bf16_t)fmaxf(h1[r], 0.f);
            }
            af[mt][c] = a;
        }

#pragma unroll
    for (int c = 0; c < 2; ++c)
#pragma unroll
        for (int mt = 0; mt < 2; ++mt)
#pragma unroll
            for (int nt = 0; nt < 4; ++nt)
                acc[mt][nt] = __builtin_amdgcn_mfma_f32_16x16x32_bf16(
                    af[mt][c], bfr[c][nt], acc[mt][nt], 0, 0, 0);
}

// ---------------------------------------------------------------------------
// Fused GEMM: out = relu(z@W1+b1) @ W2 + b2
// Block 64m x 64n, 256 thr = 4 waves = 2 m-slots (32m each) x 2 K-SLICES.
//
// R12 -- DELETE THE LDS STAGING PIPELINE (the round's variable):
// R2-R11 proved the GEMM time invariant to every lever INSIDE the
// barrier-synced staging structure (occupancy, LDS bytes, staging mech,
// barrier freq, VMEM order, h-overlap). Per-segment accounting: ~4650 cyc
// wall vs ~1100 cyc of pipe work -- the ~72% structural stall of a 2-phase
// stage+vmcnt+barrier loop (m233). But W2 is 2MB bf16 = L2-RESIDENT on
// every XCD, so LDS staging buys nothing (Common-mistake #7, m169).
// Now each wave reads its B-fragments DIRECTLY from the fragment-major
// W2f with one coalesced dwordx4 per (c,nt) -- same base per tile,
// immediate offsets. The K-loop has NO LDS, NO __syncthreads, NO vmcnt
// drains; waves are fully independent streams of 12 L2-loads + 20 MFMAs.
// LDS remains only as the 16KB split-K combine scratch (2 end barriers).
// ---------------------------------------------------------------------------
__global__ __launch_bounds__(256, 4)
void ffq_gemm_kernel(const bf16_t* __restrict__ zb,    // [8192][16]
                     const bf16_t* __restrict__ W1p,   // [2048][16] permuted
                     const bf16_t* __restrict__ W2f,   // fragment-major
                     const float* __restrict__ b2,
                     float* __restrict__ out)          // [8192][512]
{
    __shared__ float F[4096];             // split-K combine scratch (16KB)

    const int t  = threadIdx.x;           // 0..255
    const int w  = t >> 6, l = t & 63;
    const int ks = w >> 1;                // k-slice 0/1
    const int wl = w & 1;                 // m-slot of 32 rows
    const int m_base = blockIdx.y * 64;
    const int n_blk  = blockIdx.x;
    const int n_base = n_blk * 64;
    const int l15 = l & 15, lq = l >> 4;
    const int k_base = ks * 1024;

    // persistent z^T B-frags for this wave's two 16-row m-tiles
    bf16x8 zfrag[2];
#pragma unroll
    for (int mt = 0; mt < 2; ++mt) {
        zfrag[mt] = zero8();
        if (lq < 2)
            zfrag[mt] = *(const bf16x8*)(zb + (size_t)(m_base + wl * 32 + mt * 16 + l15) * 16 + lq * 8);
    }

    f32x4 acc[2][4];
#pragma unroll
    for (int mt = 0; mt < 2; ++mt)
#pragma unroll
        for (int nt = 0; nt < 4; ++nt)
            acc[mt][nt] = (f32x4){0.f, 0.f, 0.f, 0.f};

    // this slice's first fragment-major tile (tiles are contiguous in k)
    const bf16_t* tb = W2f + (size_t)(n_blk * 32 + ks * 16) * 4096;

    for (int s = 0; s < NSEG_HALF; ++s) {
        bf16x8 wf[4];
        load_wf(W1p, k_base + s * 64, l15, lq, wf);
        compute_tile(tb + (size_t)s * 4096, wf, zfrag, l, acc);
    }

    // ---- split-K combine through LDS ----
    __syncthreads();
    if (ks == 1) {
#pragma unroll
        for (int mt = 0; mt < 2; ++mt)
#pragma unroll
            for (int nt = 0; nt < 4; ++nt) {
                int idx = ((wl * 2 + mt) * 4 + nt) * 64 + l;   // lane-contig 16B
                *(f32x4*)(F + (size_t)idx * 4) = acc[mt][nt];
            }
    }
    __syncthreads();
    if (ks == 0) {
        // ---- epilogue: C/D layout col=lane&15, row=(lane>>4)*4+r ----
#pragma unroll
        for (int nt = 0; nt < 4; ++nt) {
            int col = n_base + nt * 16 + l15;
            float bias = b2[col];
#pragma unroll
            for (int mt = 0; mt < 2; ++mt) {
                int idx = ((wl * 2 + mt) * 4 + nt) * 64 + l;
                f32x4 part = *(const f32x4*)(F + (size_t)idx * 4);
#pragma unroll
                for (int r = 0; r < 4; ++r) {
                    int row = m_base + wl * 32 + mt * 16 + lq * 4 + r;
                    out[(size_t)row * N_TOT + col] = acc[mt][nt][r] + part[r] + bias;
                }
            }
        }
    }
}

extern "C" void kernel_launch(void* const* d_in, const int* in_sizes, int n_in,
                              void* d_out, int out_size, void* d_ws, size_t ws_size,
                              hipStream_t stream) {
    const float* x     = (const float*)d_in[0];
    const float* theta = (const float*)d_in[1];
    const float* W1    = (const float*)d_in[2];
    const float* b1    = (const float*)d_in[3];
    const float* W2    = (const float*)d_in[4];
    const float* b2    = (const float*)d_in[5];
    float* out = (float*)d_out;

    // ws: [0,2MB) W2f ; [2MB,2.25MB) zb[8192][16] ; then W1p[2048][16]
    const size_t W2F_BYTES = (size_t)N_TOT * K_TOT * sizeof(bf16_t);  // 2 MB
    const size_t ZB_BYTES  = (size_t)M_TOT * 16 * sizeof(bf16_t);     // 256 KB

    bf16_t* W2f = (bf16_t*)d_ws;
    bf16_t* zb  = (bf16_t*)((char*)d_ws + W2F_BYTES);
    bf16_t* W1p = (bf16_t*)((char*)d_ws + W2F_BYTES + ZB_BYTES);

    prep4_kernel<<<296, 256, 0, stream>>>(x, theta, W1, b1, W2, W2f, zb, W1p);

    dim3 grid(N_TOT / 64, M_TOT / 64);    // (8, 128) = 1024 blocks
    ffq_gemm_kernel<<<grid, 256, 0, stream>>>(zb, W1p, W2f, b2, out);
}